// Round 10
// baseline (1086.727 us; speedup 1.0000x reference)
//
#include <hip/hip_runtime.h>

// LSTMTrafficPredictor: fused 2-layer LSTM + FC head via MFMA (bf16 hi/lo split).
// B=2048, T=512, IN=4, H1=64, H2=32, FC=16, OUT=1.
// R10: R8/R9 accidentally ran grid = 2048/8 = 256 blocks = ONE block per CU:
// the 1-barrier design had no overlap partner, every step exposed the full
// read->MFMA->activation chain (occupancy 23.5% = 8 waves/CU). Fix:
//   MB 4, grid 512 -> 2 blocks/CU; __launch_bounds__(512,4) (128 regs/wave,
//   4 waves/SIMD = full 512-reg pool). To fit the cap: fragment reads are
//   STREAMED per-ks (live z-frags 32->8 VGPRs); weights stay AGPR-pinned (80).
// Also: 1/x -> __builtin_amdgcn_rcpf (kills ~10-instr v_div_* expansions,
// ~150 VALU/wave/step), acc2 chain split 12-deep -> 2x6-deep.
// Structure otherwise identical to R9 (verified absmax 6.1e-5):
//   k-map (K=128): [x(0..3) | h1(4..67) | bias-one(68) | 0(69..95) | h2(96..127)]
//   L1: 2 tiles/wave (unit w*8+nt*4+quad, acc[rg]=gate rg), ks 0..2
//   L2: 1 tile/wave  (unit w*4+quad,      acc[rg]=gate rg), ks 0..3
//   z offset(k,n) = (k>>5)*512 + (((k>>3)&3)*16+n)*8 + (k&7); frag read = lane*8.

#define T_LEN 512
#define IN_F  4
#define H1    64
#define H2    32
#define FCN   16
#define MB    4
#define BLK   512

typedef __attribute__((ext_vector_type(8))) short s8b;  // 8 bf16 = 4 VGPR
typedef __attribute__((ext_vector_type(4))) float f4;   // MFMA acc
typedef __attribute__((ext_vector_type(4))) int   i4;   // 4 dwords (pin unit)

union S8U { s8b v; i4 d; unsigned short u[8]; };

// Pin 4 consecutive regs into AGPRs; asm def kills rematerialization.
#define APIN4(x) asm volatile("" : "+a"((x).d))

__device__ __forceinline__ float rcp_(float x) { return __builtin_amdgcn_rcpf(x); }
__device__ __forceinline__ float sigm(float x)  { return rcp_(1.0f + __expf(-x)); }
__device__ __forceinline__ float tanh_(float x) { return 1.0f - 2.0f * rcp_(__expf(2.0f * x) + 1.0f); }

__device__ __forceinline__ unsigned short bf16_rne(float f) {
    unsigned u = __float_as_uint(f);
    u = u + 0x7FFFu + ((u >> 16) & 1u);
    return (unsigned short)(u >> 16);
}
__device__ __forceinline__ float bf16_f(unsigned short h) {
    return __uint_as_float(((unsigned)h) << 16);
}

__global__ __launch_bounds__(BLK, 4)
void lstm_mfma(const float* __restrict__ x,
               const float* __restrict__ Wih1, const float* __restrict__ Whh1,
               const float* __restrict__ bih1, const float* __restrict__ bhh1,
               const float* __restrict__ Wih2, const float* __restrict__ Whh2,
               const float* __restrict__ bih2, const float* __restrict__ bhh2,
               const float* __restrict__ fc1_w, const float* __restrict__ fc1_b,
               const float* __restrict__ fc2_w, const float* __restrict__ fc2_b,
               float* __restrict__ out)
{
    __shared__ __align__(16) unsigned short zz[2][2][2048];  // [pp][hi/lo][4ks*512] 16 KB
    __shared__ __align__(16) float h2f[MB * H2];
    __shared__ __align__(16) float fcs[MB * FCN];

    const int t    = threadIdx.x;
    const int lane = t & 63;
    const int w    = t >> 6;      // wave 0..7
    const int col  = lane & 15;   // batch col (valid < MB) / A-frag row
    const int quad = lane >> 4;
    const int b0   = blockIdx.x * MB;

    // ---- weight fragments (gate-complete interleaved mapping) ----
    S8U wf1h[2][3], wf1l[2][3];   // layer1: 2 tiles x ks 0..2
    S8U wf2h[4],    wf2l[4];      // layer2: 1 tile  x ks 0..3
    #pragma unroll
    for (int nt = 0; nt < 2; ++nt) {
        const int r1 = (col & 3) * 64 + w * 8 + nt * 4 + (col >> 2);
        #pragma unroll
        for (int ks = 0; ks < 3; ++ks) {
            #pragma unroll
            for (int j = 0; j < 8; ++j) {
                const int k = ks * 32 + quad * 8 + j;
                float wv;
                if      (k < IN_F)       wv = Wih1[r1 * IN_F + k];
                else if (k < IN_F + H1)  wv = Whh1[r1 * H1 + (k - IN_F)];
                else if (k == IN_F + H1) wv = bih1[r1] + bhh1[r1];   // bias col
                else                     wv = 0.f;
                const unsigned short hh = bf16_rne(wv);
                wf1h[nt][ks].u[j] = hh;
                wf1l[nt][ks].u[j] = bf16_rne(wv - bf16_f(hh));
            }
        }
    }
    {
        const int r2 = (col & 3) * 32 + w * 4 + (col >> 2);
        #pragma unroll
        for (int ks = 0; ks < 4; ++ks) {
            #pragma unroll
            for (int j = 0; j < 8; ++j) {
                const int k = ks * 32 + quad * 8 + j;
                float wv;
                if      (k >= IN_F && k < IN_F + H1) wv = Wih2[r2 * H1 + (k - IN_F)];
                else if (k == IN_F + H1)             wv = bih2[r2] + bhh2[r2]; // bias col
                else if (k >= 96)                    wv = Whh2[r2 * H2 + (k - 96)];
                else                                 wv = 0.f;
                const unsigned short hh = bf16_rne(wv);
                wf2h[ks].u[j] = hh;
                wf2l[ks].u[j] = bf16_rne(wv - bf16_f(hh));
            }
        }
    }
    // ---- PIN all fragments into AGPRs ----
    #pragma unroll
    for (int nt = 0; nt < 2; ++nt)
        #pragma unroll
        for (int ks = 0; ks < 3; ++ks) { APIN4(wf1h[nt][ks]); APIN4(wf1l[nt][ks]); }
    #pragma unroll
    for (int ks = 0; ks < 4; ++ks) { APIN4(wf2h[ks]); APIN4(wf2l[ks]); }

    // ---- init LDS: zero z; bias-one col (both pp); x(0) ----
    {
        int* pz = (int*)zz;
        #pragma unroll
        for (int i = 0; i < 8; ++i) pz[t + i * BLK] = 0;
    }
    __syncthreads();
    if (t < 16) {                           // off(k=68,n) = 1024 + n*8 + 4
        zz[0][0][1024 + t * 8 + 4] = 0x3F80;
        zz[1][0][1024 + t * 8 + 4] = 0x3F80;
    }
    if (t < MB * IN_F) {
        const int n = t >> 2, f = t & 3;
        const float xv = x[(size_t)(b0 + n) * T_LEN * IN_F + f];
        const unsigned short xh = bf16_rne(xv);
        zz[0][0][n * 8 + f] = xh;           // off(k=f,n) = n*8 + f
        zz[0][1][n * 8 + f] = bf16_rne(xv - bf16_f(xh));
    }
    float c1[2] = {0.f, 0.f};   // layer1 units w*8+nt*4+quad, batch col
    float c2    = 0.f;          // layer2 unit  w*4+quad,      batch col

    // precomputed store offsets (element index)
    const int u1a  = w * 8 + quad;                 // nt=0 unit
    const int u1b  = w * 8 + 4 + quad;             // nt=1 unit
    const int kA0  = IN_F + u1a, kA1 = IN_F + u1b;
    const int off1a = (kA0 >> 5) * 512 + (((kA0 >> 3) & 3) * 16 + col) * 8 + (kA0 & 7);
    const int off1b = (kA1 >> 5) * 512 + (((kA1 >> 3) & 3) * 16 + col) * 8 + (kA1 & 7);
    const int u2    = w * 4 + quad;
    const int off2  = 1536 + (((u2 >> 3) & 3) * 16 + col) * 8 + (u2 & 7);
    const int offF  = lane * 8;                    // frag read base
    __syncthreads();

    // ================= main recurrence: ONE barrier per step =================
    #pragma unroll 1
    for (int s = 0; s < T_LEN; ++s) {
        const int p = s & 1, np = p ^ 1;

        float xnext = 0.f;
        if (t < MB * IN_F && s < T_LEN - 1)
            xnext = x[(size_t)(b0 + (t >> 2)) * T_LEN * IN_F + (s + 1) * IN_F + (t & 3)];

        // ---- streamed per-ks frag reads + MFMA (live frags: 8 VGPR) ----
        f4 acc1[2] = {{0,0,0,0},{0,0,0,0}};
        f4 acc2a = {0,0,0,0}, acc2b = {0,0,0,0};
        #pragma unroll
        for (int ks = 0; ks < 4; ++ks) {
            const s8b zh = *(const s8b*)(&zz[p][0][0] + ks * 512 + offF);
            const s8b zl = *(const s8b*)(&zz[p][1][0] + ks * 512 + offF);
            if (ks < 3) {
                #pragma unroll
                for (int nt = 0; nt < 2; ++nt) {
                    acc1[nt] = __builtin_amdgcn_mfma_f32_16x16x32_bf16(wf1h[nt][ks].v, zh, acc1[nt], 0, 0, 0);
                    acc1[nt] = __builtin_amdgcn_mfma_f32_16x16x32_bf16(wf1h[nt][ks].v, zl, acc1[nt], 0, 0, 0);
                    acc1[nt] = __builtin_amdgcn_mfma_f32_16x16x32_bf16(wf1l[nt][ks].v, zh, acc1[nt], 0, 0, 0);
                }
            }
            if (ks < 2) {
                acc2a = __builtin_amdgcn_mfma_f32_16x16x32_bf16(wf2h[ks].v, zh, acc2a, 0, 0, 0);
                acc2a = __builtin_amdgcn_mfma_f32_16x16x32_bf16(wf2h[ks].v, zl, acc2a, 0, 0, 0);
                acc2a = __builtin_amdgcn_mfma_f32_16x16x32_bf16(wf2l[ks].v, zh, acc2a, 0, 0, 0);
            } else {
                acc2b = __builtin_amdgcn_mfma_f32_16x16x32_bf16(wf2h[ks].v, zh, acc2b, 0, 0, 0);
                acc2b = __builtin_amdgcn_mfma_f32_16x16x32_bf16(wf2h[ks].v, zl, acc2b, 0, 0, 0);
                acc2b = __builtin_amdgcn_mfma_f32_16x16x32_bf16(wf2l[ks].v, zh, acc2b, 0, 0, 0);
            }
        }

        // ---- layer1 activations in-register (acc[rg] = gate rg: i,f,g,o) ----
        #pragma unroll
        for (int nt = 0; nt < 2; ++nt) {
            const float I = sigm(acc1[nt][0]);
            const float F = sigm(acc1[nt][1]);
            const float G = tanh_(acc1[nt][2]);
            const float O = sigm(acc1[nt][3]);
            c1[nt] = fmaf(F, c1[nt], I * G);
            const float h = O * tanh_(c1[nt]);
            const unsigned short hh = bf16_rne(h);
            const unsigned short hl = bf16_rne(h - bf16_f(hh));
            if (col < MB) {
                const int o = nt ? off1b : off1a;
                zz[np][0][o] = hh;
                zz[np][1][o] = hl;
            }
        }

        // ---- layer2 activation for step s-1 (bias came via bias column) ----
        if (s > 0) {
            const float I = sigm(acc2a[0] + acc2b[0]);
            const float F = sigm(acc2a[1] + acc2b[1]);
            const float G = tanh_(acc2a[2] + acc2b[2]);
            const float O = sigm(acc2a[3] + acc2b[3]);
            c2 = fmaf(F, c2, I * G);
            const float h = O * tanh_(c2);
            if (col < MB) {
                const unsigned short hh = bf16_rne(h);
                zz[np][0][off2] = hh;
                zz[np][1][off2] = bf16_rne(h - bf16_f(hh));
            }
        }

        // ---- x(s+1) ----
        if (t < MB * IN_F && s < T_LEN - 1) {
            const unsigned short xh = bf16_rne(xnext);
            zz[np][0][(t >> 2) * 8 + (t & 3)] = xh;
            zz[np][1][(t >> 2) * 8 + (t & 3)] = bf16_rne(xnext - bf16_f(xh));
        }
        __syncthreads();
    }

    // ================= epilogue: layer2 step T-1 =================
    {
        // loop ended with s=511 (p=1, np=0): z[0] holds h1(511), h2(510).
        f4 acc2a = {0,0,0,0}, acc2b = {0,0,0,0};
        #pragma unroll
        for (int ks = 0; ks < 4; ++ks) {
            const s8b zh = *(const s8b*)(&zz[0][0][0] + ks * 512 + offF);
            const s8b zl = *(const s8b*)(&zz[0][1][0] + ks * 512 + offF);
            if (ks < 2) {
                acc2a = __builtin_amdgcn_mfma_f32_16x16x32_bf16(wf2h[ks].v, zh, acc2a, 0, 0, 0);
                acc2a = __builtin_amdgcn_mfma_f32_16x16x32_bf16(wf2h[ks].v, zl, acc2a, 0, 0, 0);
                acc2a = __builtin_amdgcn_mfma_f32_16x16x32_bf16(wf2l[ks].v, zh, acc2a, 0, 0, 0);
            } else {
                acc2b = __builtin_amdgcn_mfma_f32_16x16x32_bf16(wf2h[ks].v, zh, acc2b, 0, 0, 0);
                acc2b = __builtin_amdgcn_mfma_f32_16x16x32_bf16(wf2h[ks].v, zl, acc2b, 0, 0, 0);
                acc2b = __builtin_amdgcn_mfma_f32_16x16x32_bf16(wf2l[ks].v, zh, acc2b, 0, 0, 0);
            }
        }
        const float I = sigm(acc2a[0] + acc2b[0]);
        const float F = sigm(acc2a[1] + acc2b[1]);
        const float G = tanh_(acc2a[2] + acc2b[2]);
        const float O = sigm(acc2a[3] + acc2b[3]);
        c2 = fmaf(F, c2, I * G);
        if (col < MB) h2f[col * H2 + u2] = O * tanh_(c2);
    }
    __syncthreads();

    // ================= FC head =================
    if (t < MB * FCN) {
        const int b = t >> 4, j = t & 15;
        float s1 = fc1_b[j];
        #pragma unroll
        for (int k = 0; k < H2; ++k)
            s1 = fmaf(fc1_w[j * H2 + k], h2f[b * H2 + k], s1);
        fcs[b * FCN + j] = fmaxf(s1, 0.f);
    }
    __syncthreads();
    if (t < MB) {
        float s2 = fc2_b[0];
        #pragma unroll
        for (int j = 0; j < FCN; ++j)
            s2 = fmaf(fc2_w[j], fcs[t * FCN + j], s2);
        out[b0 + t] = s2;
    }
}

extern "C" void kernel_launch(void* const* d_in, const int* in_sizes, int n_in,
                              void* d_out, int out_size, void* d_ws, size_t ws_size,
                              hipStream_t stream) {
    const float* x     = (const float*)d_in[0];
    const float* Wih1  = (const float*)d_in[1];
    const float* Whh1  = (const float*)d_in[2];
    const float* bih1  = (const float*)d_in[3];
    const float* bhh1  = (const float*)d_in[4];
    const float* Wih2  = (const float*)d_in[5];
    const float* Whh2  = (const float*)d_in[6];
    const float* bih2  = (const float*)d_in[7];
    const float* bhh2  = (const float*)d_in[8];
    const float* fc1_w = (const float*)d_in[9];
    const float* fc1_b = (const float*)d_in[10];
    const float* fc2_w = (const float*)d_in[11];
    const float* fc2_b = (const float*)d_in[12];
    float* out = (float*)d_out;

    const int n_batch = 2048;
    dim3 grid(n_batch / MB), block(BLK);
    lstm_mfma<<<grid, block, 0, stream>>>(x, Wih1, Whh1, bih1, bhh1,
                                          Wih2, Whh2, bih2, bhh2,
                                          fc1_w, fc1_b, fc2_w, fc2_b, out);
}

// Round 11
// 601.848 us; speedup vs baseline: 1.8057x; 1.8057x over previous
//
#include <hip/hip_runtime.h>

// LSTMTrafficPredictor: fused 2-layer LSTM + FC head via MFMA (bf16 hi/lo split).
// B=2048, T=512, IN=4, H1=64, H2=32, FC=16, OUT=1.
// R11 = R9's launch config (the verified no-spill point: MB=8, BLK=512,
// grid=256, launch_bounds(512,2), VGPR 112, WRITE_SIZE 8KB) + R10's two
// individually-validated micro-fixes:
//   (a) 1/x -> v_rcp_f32 (R9 had 15 full v_div_* expansions/thread/step,
//       ~600 cyc/SIMD/step; R10 validated identical absmax 6.1e-5),
//   (b) streamed per-ks frag reads + split acc2 chain (fewer live VGPRs,
//       4 independent MFMA chains).
// R10's launch_bounds(512,4)/128-reg cap spilled to scratch (WRITE_SIZE
// 10 MB): 80 AGPR-pinned weight regs force <=2 waves/SIMD. Do not revisit.
// Structure (verified absmax 6.1e-5 across R8/R9/R10):
//   k-map (K=128): [x(0..3) | h1(4..67) | bias-one(68) | 0(69..95) | h2(96..127)]
//   L1: 2 tiles/wave (unit w*8+nt*4+quad, acc[rg]=gate rg), ks 0..2
//   L2: 1 tile/wave  (unit w*4+quad,      acc[rg]=gate rg), ks 0..3
//   z offset(k,n) = (k>>5)*512 + (((k>>3)&3)*16+n)*8 + (k&7); frag read = lane*8.

#define T_LEN 512
#define IN_F  4
#define H1    64
#define H2    32
#define FCN   16
#define MB    8
#define BLK   512

typedef __attribute__((ext_vector_type(8))) short s8b;  // 8 bf16 = 4 VGPR
typedef __attribute__((ext_vector_type(4))) float f4;   // MFMA acc
typedef __attribute__((ext_vector_type(4))) int   i4;   // 4 dwords (pin unit)

union S8U { s8b v; i4 d; unsigned short u[8]; };

// Pin 4 consecutive regs into AGPRs; asm def kills rematerialization.
#define APIN4(x) asm volatile("" : "+a"((x).d))

__device__ __forceinline__ float rcp_(float x) { return __builtin_amdgcn_rcpf(x); }
__device__ __forceinline__ float sigm(float x)  { return rcp_(1.0f + __expf(-x)); }
__device__ __forceinline__ float tanh_(float x) { return 1.0f - 2.0f * rcp_(__expf(2.0f * x) + 1.0f); }

__device__ __forceinline__ unsigned short bf16_rne(float f) {
    unsigned u = __float_as_uint(f);
    u = u + 0x7FFFu + ((u >> 16) & 1u);
    return (unsigned short)(u >> 16);
}
__device__ __forceinline__ float bf16_f(unsigned short h) {
    return __uint_as_float(((unsigned)h) << 16);
}

__global__ __launch_bounds__(BLK, 2)
void lstm_mfma(const float* __restrict__ x,
               const float* __restrict__ Wih1, const float* __restrict__ Whh1,
               const float* __restrict__ bih1, const float* __restrict__ bhh1,
               const float* __restrict__ Wih2, const float* __restrict__ Whh2,
               const float* __restrict__ bih2, const float* __restrict__ bhh2,
               const float* __restrict__ fc1_w, const float* __restrict__ fc1_b,
               const float* __restrict__ fc2_w, const float* __restrict__ fc2_b,
               float* __restrict__ out)
{
    __shared__ __align__(16) unsigned short zz[2][2][2048];  // [pp][hi/lo][4ks*512] 16 KB
    __shared__ __align__(16) float h2f[MB * H2];
    __shared__ __align__(16) float fcs[MB * FCN];

    const int t    = threadIdx.x;
    const int lane = t & 63;
    const int w    = t >> 6;      // wave 0..7
    const int col  = lane & 15;   // batch col (valid < MB) / A-frag row
    const int quad = lane >> 4;
    const int b0   = blockIdx.x * MB;

    // ---- weight fragments (gate-complete interleaved mapping) ----
    S8U wf1h[2][3], wf1l[2][3];   // layer1: 2 tiles x ks 0..2
    S8U wf2h[4],    wf2l[4];      // layer2: 1 tile  x ks 0..3
    #pragma unroll
    for (int nt = 0; nt < 2; ++nt) {
        const int r1 = (col & 3) * 64 + w * 8 + nt * 4 + (col >> 2);
        #pragma unroll
        for (int ks = 0; ks < 3; ++ks) {
            #pragma unroll
            for (int j = 0; j < 8; ++j) {
                const int k = ks * 32 + quad * 8 + j;
                float wv;
                if      (k < IN_F)       wv = Wih1[r1 * IN_F + k];
                else if (k < IN_F + H1)  wv = Whh1[r1 * H1 + (k - IN_F)];
                else if (k == IN_F + H1) wv = bih1[r1] + bhh1[r1];   // bias col
                else                     wv = 0.f;
                const unsigned short hh = bf16_rne(wv);
                wf1h[nt][ks].u[j] = hh;
                wf1l[nt][ks].u[j] = bf16_rne(wv - bf16_f(hh));
            }
        }
    }
    {
        const int r2 = (col & 3) * 32 + w * 4 + (col >> 2);
        #pragma unroll
        for (int ks = 0; ks < 4; ++ks) {
            #pragma unroll
            for (int j = 0; j < 8; ++j) {
                const int k = ks * 32 + quad * 8 + j;
                float wv;
                if      (k >= IN_F && k < IN_F + H1) wv = Wih2[r2 * H1 + (k - IN_F)];
                else if (k == IN_F + H1)             wv = bih2[r2] + bhh2[r2]; // bias col
                else if (k >= 96)                    wv = Whh2[r2 * H2 + (k - 96)];
                else                                 wv = 0.f;
                const unsigned short hh = bf16_rne(wv);
                wf2h[ks].u[j] = hh;
                wf2l[ks].u[j] = bf16_rne(wv - bf16_f(hh));
            }
        }
    }
    // ---- PIN all fragments into AGPRs (kills in-loop rematerialization) ----
    #pragma unroll
    for (int nt = 0; nt < 2; ++nt)
        #pragma unroll
        for (int ks = 0; ks < 3; ++ks) { APIN4(wf1h[nt][ks]); APIN4(wf1l[nt][ks]); }
    #pragma unroll
    for (int ks = 0; ks < 4; ++ks) { APIN4(wf2h[ks]); APIN4(wf2l[ks]); }

    // ---- init LDS: zero z; bias-one col (both pp); x(0) ----
    {
        int* pz = (int*)zz;
        #pragma unroll
        for (int i = 0; i < 8; ++i) pz[t + i * BLK] = 0;
    }
    __syncthreads();
    if (t < 16) {                           // off(k=68,n) = 1024 + n*8 + 4
        zz[0][0][1024 + t * 8 + 4] = 0x3F80;
        zz[1][0][1024 + t * 8 + 4] = 0x3F80;
    }
    if (t < MB * IN_F) {
        const int n = t >> 2, f = t & 3;
        const float xv = x[(size_t)(b0 + n) * T_LEN * IN_F + f];
        const unsigned short xh = bf16_rne(xv);
        zz[0][0][n * 8 + f] = xh;           // off(k=f,n) = n*8 + f
        zz[0][1][n * 8 + f] = bf16_rne(xv - bf16_f(xh));
    }
    float c1[2] = {0.f, 0.f};   // layer1 units w*8+nt*4+quad, batch col
    float c2    = 0.f;          // layer2 unit  w*4+quad,      batch col

    // precomputed store offsets (element index)
    const int u1a  = w * 8 + quad;                 // nt=0 unit
    const int u1b  = w * 8 + 4 + quad;             // nt=1 unit
    const int kA0  = IN_F + u1a, kA1 = IN_F + u1b;
    const int off1a = (kA0 >> 5) * 512 + (((kA0 >> 3) & 3) * 16 + col) * 8 + (kA0 & 7);
    const int off1b = (kA1 >> 5) * 512 + (((kA1 >> 3) & 3) * 16 + col) * 8 + (kA1 & 7);
    const int u2    = w * 4 + quad;
    const int off2  = 1536 + (((u2 >> 3) & 3) * 16 + col) * 8 + (u2 & 7);
    const int offF  = lane * 8;                    // frag read base
    __syncthreads();

    // ================= main recurrence: ONE barrier per step =================
    #pragma unroll 1
    for (int s = 0; s < T_LEN; ++s) {
        const int p = s & 1, np = p ^ 1;

        float xnext = 0.f;
        if (t < MB * IN_F && s < T_LEN - 1)
            xnext = x[(size_t)(b0 + (t >> 2)) * T_LEN * IN_F + (s + 1) * IN_F + (t & 3)];

        // ---- streamed per-ks frag reads + MFMA (live frags: 8 VGPR) ----
        f4 acc1[2] = {{0,0,0,0},{0,0,0,0}};
        f4 acc2a = {0,0,0,0}, acc2b = {0,0,0,0};
        #pragma unroll
        for (int ks = 0; ks < 4; ++ks) {
            const s8b zh = *(const s8b*)(&zz[p][0][0] + ks * 512 + offF);
            const s8b zl = *(const s8b*)(&zz[p][1][0] + ks * 512 + offF);
            if (ks < 3) {
                #pragma unroll
                for (int nt = 0; nt < 2; ++nt) {
                    acc1[nt] = __builtin_amdgcn_mfma_f32_16x16x32_bf16(wf1h[nt][ks].v, zh, acc1[nt], 0, 0, 0);
                    acc1[nt] = __builtin_amdgcn_mfma_f32_16x16x32_bf16(wf1h[nt][ks].v, zl, acc1[nt], 0, 0, 0);
                    acc1[nt] = __builtin_amdgcn_mfma_f32_16x16x32_bf16(wf1l[nt][ks].v, zh, acc1[nt], 0, 0, 0);
                }
            }
            if (ks < 2) {
                acc2a = __builtin_amdgcn_mfma_f32_16x16x32_bf16(wf2h[ks].v, zh, acc2a, 0, 0, 0);
                acc2a = __builtin_amdgcn_mfma_f32_16x16x32_bf16(wf2h[ks].v, zl, acc2a, 0, 0, 0);
                acc2a = __builtin_amdgcn_mfma_f32_16x16x32_bf16(wf2l[ks].v, zh, acc2a, 0, 0, 0);
            } else {
                acc2b = __builtin_amdgcn_mfma_f32_16x16x32_bf16(wf2h[ks].v, zh, acc2b, 0, 0, 0);
                acc2b = __builtin_amdgcn_mfma_f32_16x16x32_bf16(wf2h[ks].v, zl, acc2b, 0, 0, 0);
                acc2b = __builtin_amdgcn_mfma_f32_16x16x32_bf16(wf2l[ks].v, zh, acc2b, 0, 0, 0);
            }
        }

        // ---- layer1 activations in-register (acc[rg] = gate rg: i,f,g,o) ----
        #pragma unroll
        for (int nt = 0; nt < 2; ++nt) {
            const float I = sigm(acc1[nt][0]);
            const float F = sigm(acc1[nt][1]);
            const float G = tanh_(acc1[nt][2]);
            const float O = sigm(acc1[nt][3]);
            c1[nt] = fmaf(F, c1[nt], I * G);
            const float h = O * tanh_(c1[nt]);
            const unsigned short hh = bf16_rne(h);
            const unsigned short hl = bf16_rne(h - bf16_f(hh));
            if (col < MB) {
                const int o = nt ? off1b : off1a;
                zz[np][0][o] = hh;
                zz[np][1][o] = hl;
            }
        }

        // ---- layer2 activation for step s-1 (bias came via bias column) ----
        if (s > 0) {
            const float I = sigm(acc2a[0] + acc2b[0]);
            const float F = sigm(acc2a[1] + acc2b[1]);
            const float G = tanh_(acc2a[2] + acc2b[2]);
            const float O = sigm(acc2a[3] + acc2b[3]);
            c2 = fmaf(F, c2, I * G);
            const float h = O * tanh_(c2);
            if (col < MB) {
                const unsigned short hh = bf16_rne(h);
                zz[np][0][off2] = hh;
                zz[np][1][off2] = bf16_rne(h - bf16_f(hh));
            }
        }

        // ---- x(s+1) ----
        if (t < MB * IN_F && s < T_LEN - 1) {
            const unsigned short xh = bf16_rne(xnext);
            zz[np][0][(t >> 2) * 8 + (t & 3)] = xh;
            zz[np][1][(t >> 2) * 8 + (t & 3)] = bf16_rne(xnext - bf16_f(xh));
        }
        __syncthreads();
    }

    // ================= epilogue: layer2 step T-1 =================
    {
        // loop ended with s=511 (p=1, np=0): z[0] holds h1(511), h2(510).
        f4 acc2a = {0,0,0,0}, acc2b = {0,0,0,0};
        #pragma unroll
        for (int ks = 0; ks < 4; ++ks) {
            const s8b zh = *(const s8b*)(&zz[0][0][0] + ks * 512 + offF);
            const s8b zl = *(const s8b*)(&zz[0][1][0] + ks * 512 + offF);
            if (ks < 2) {
                acc2a = __builtin_amdgcn_mfma_f32_16x16x32_bf16(wf2h[ks].v, zh, acc2a, 0, 0, 0);
                acc2a = __builtin_amdgcn_mfma_f32_16x16x32_bf16(wf2h[ks].v, zl, acc2a, 0, 0, 0);
                acc2a = __builtin_amdgcn_mfma_f32_16x16x32_bf16(wf2l[ks].v, zh, acc2a, 0, 0, 0);
            } else {
                acc2b = __builtin_amdgcn_mfma_f32_16x16x32_bf16(wf2h[ks].v, zh, acc2b, 0, 0, 0);
                acc2b = __builtin_amdgcn_mfma_f32_16x16x32_bf16(wf2h[ks].v, zl, acc2b, 0, 0, 0);
                acc2b = __builtin_amdgcn_mfma_f32_16x16x32_bf16(wf2l[ks].v, zh, acc2b, 0, 0, 0);
            }
        }
        const float I = sigm(acc2a[0] + acc2b[0]);
        const float F = sigm(acc2a[1] + acc2b[1]);
        const float G = tanh_(acc2a[2] + acc2b[2]);
        const float O = sigm(acc2a[3] + acc2b[3]);
        c2 = fmaf(F, c2, I * G);
        if (col < MB) h2f[col * H2 + u2] = O * tanh_(c2);
    }
    __syncthreads();

    // ================= FC head =================
    if (t < MB * FCN) {
        const int b = t >> 4, j = t & 15;
        float s1 = fc1_b[j];
        #pragma unroll
        for (int k = 0; k < H2; ++k)
            s1 = fmaf(fc1_w[j * H2 + k], h2f[b * H2 + k], s1);
        fcs[b * FCN + j] = fmaxf(s1, 0.f);
    }
    __syncthreads();
    if (t < MB) {
        float s2 = fc2_b[0];
        #pragma unroll
        for (int j = 0; j < FCN; ++j)
            s2 = fmaf(fc2_w[j], fcs[t * FCN + j], s2);
        out[b0 + t] = s2;
    }
}

extern "C" void kernel_launch(void* const* d_in, const int* in_sizes, int n_in,
                              void* d_out, int out_size, void* d_ws, size_t ws_size,
                              hipStream_t stream) {
    const float* x     = (const float*)d_in[0];
    const float* Wih1  = (const float*)d_in[1];
    const float* Whh1  = (const float*)d_in[2];
    const float* bih1  = (const float*)d_in[3];
    const float* bhh1  = (const float*)d_in[4];
    const float* Wih2  = (const float*)d_in[5];
    const float* Whh2  = (const float*)d_in[6];
    const float* bih2  = (const float*)d_in[7];
    const float* bhh2  = (const float*)d_in[8];
    const float* fc1_w = (const float*)d_in[9];
    const float* fc1_b = (const float*)d_in[10];
    const float* fc2_w = (const float*)d_in[11];
    const float* fc2_b = (const float*)d_in[12];
    float* out = (float*)d_out;

    const int n_batch = 2048;
    dim3 grid(n_batch / MB), block(BLK);
    lstm_mfma<<<grid, block, 0, stream>>>(x, Wih1, Whh1, bih1, bhh1,
                                          Wih2, Whh2, bih2, bhh2,
                                          fc1_w, fc1_b, fc2_w, fc2_b, out);
}

// Round 12
// 597.407 us; speedup vs baseline: 1.8191x; 1.0074x over previous
//
#include <hip/hip_runtime.h>

// LSTMTrafficPredictor: fused 2-layer LSTM + FC head via MFMA (bf16 hi/lo split).
// B=2048, T=512, IN=4, H1=64, H2=32, FC=16, OUT=1.
// R12 = R11 (601us; MB=8, BLK=512, grid=256, bounds(512,2), AGPR-pinned
// weights — the verified no-spill point) + three issue/latency cuts:
//  1. z remap [h1(0..63) | x(64..67) | bias(68) | pad(69..95) | h2(96..127)]:
//     L2 reads ks{0,1,3} only (skips x/bias block) — its bias moves into the
//     MFMA C-init (acc2a starts = {bI,bF,bG,bO}, free). MFMA 30 -> 27/wave/step.
//  2. Split compensation chains: A(hi@zhi, depth3) + B(hi@zlo+lo@zhi, depth6)
//     per tile -> 6 independent chains (was 4, depth 9). Gates = A+B (fp32 add).
//  3. Unroll step loop by 2: ping-pong p compile-time -> LDS addrs are
//     single vaddr + immediate offsets; x pointer bumped not recomputed.
// Counter accounting note (R11): VALUBusy INCLUDES v_mfma issue. R11's 60% =
// 37.5% MFMA + ~20% real VALU; remaining ~40% of step = chain/barrier stall.
// Precision: v = hi+lo (bf16); gate = Whi@zhi + Whi@zlo + Wlo@zhi (absmax 6e-5).
//   L1: 2 tiles/wave (unit w*8+nt*4+quad, acc[rg]=gate rg), ks 0..2
//   L2: 1 tile/wave  (unit w*4+quad,      acc[rg]=gate rg), ks {0,1,3}
//   z offset(k,n) = (k>>5)*512 + (((k>>3)&3)*16+n)*8 + (k&7); frag read = lane*8.

#define T_LEN 512
#define IN_F  4
#define H1    64
#define H2    32
#define FCN   16
#define MB    8
#define BLK   512

typedef __attribute__((ext_vector_type(8))) short s8b;  // 8 bf16 = 4 VGPR
typedef __attribute__((ext_vector_type(4))) float f4;   // MFMA acc
typedef __attribute__((ext_vector_type(4))) int   i4;   // 4 dwords (pin unit)

union S8U { s8b v; i4 d; unsigned short u[8]; };
union F4U { f4 v; i4 d; float f[4]; };

// Pin 4 consecutive regs into AGPRs; asm def kills rematerialization.
#define APIN4(x) asm volatile("" : "+a"((x).d))

__device__ __forceinline__ float rcp_(float x) { return __builtin_amdgcn_rcpf(x); }
__device__ __forceinline__ float sigm(float x)  { return rcp_(1.0f + __expf(-x)); }
__device__ __forceinline__ float tanh_(float x) { return 1.0f - 2.0f * rcp_(__expf(2.0f * x) + 1.0f); }

__device__ __forceinline__ unsigned short bf16_rne(float f) {
    unsigned u = __float_as_uint(f);
    u = u + 0x7FFFu + ((u >> 16) & 1u);
    return (unsigned short)(u >> 16);
}
__device__ __forceinline__ float bf16_f(unsigned short h) {
    return __uint_as_float(((unsigned)h) << 16);
}

// ---- step-body macros (P = read buffer, NP = write buffer, compile-time) ----
#define STEP_MFMA(P)                                                            \
    f4 a1A[2] = {{0,0,0,0},{0,0,0,0}}, a1B[2] = {{0,0,0,0},{0,0,0,0}};          \
    f4 ac2a = bb2.v, ac2b = {0,0,0,0};                                          \
    _Pragma("unroll")                                                           \
    for (int ks = 0; ks < 4; ++ks) {                                            \
        const s8b zh = *(const s8b*)(&zz[P][0][0] + ks * 512 + offF);           \
        const s8b zl = *(const s8b*)(&zz[P][1][0] + ks * 512 + offF);           \
        if (ks < 3) {                                                           \
            _Pragma("unroll")                                                   \
            for (int nt = 0; nt < 2; ++nt) {                                    \
                a1A[nt] = __builtin_amdgcn_mfma_f32_16x16x32_bf16(wf1h[nt][ks].v, zh, a1A[nt], 0, 0, 0); \
                a1B[nt] = __builtin_amdgcn_mfma_f32_16x16x32_bf16(wf1h[nt][ks].v, zl, a1B[nt], 0, 0, 0); \
                a1B[nt] = __builtin_amdgcn_mfma_f32_16x16x32_bf16(wf1l[nt][ks].v, zh, a1B[nt], 0, 0, 0); \
            }                                                                   \
        }                                                                       \
        if (ks != 2) {                                                          \
            const int kf = (ks < 2) ? ks : 2;                                   \
            ac2a = __builtin_amdgcn_mfma_f32_16x16x32_bf16(wf2h[kf].v, zh, ac2a, 0, 0, 0); \
            ac2b = __builtin_amdgcn_mfma_f32_16x16x32_bf16(wf2h[kf].v, zl, ac2b, 0, 0, 0); \
            ac2b = __builtin_amdgcn_mfma_f32_16x16x32_bf16(wf2l[kf].v, zh, ac2b, 0, 0, 0); \
        }                                                                       \
    }

#define STEP_ACT1(NP)                                                           \
    _Pragma("unroll")                                                           \
    for (int nt = 0; nt < 2; ++nt) {                                            \
        const float I = sigm(a1A[nt][0] + a1B[nt][0]);                          \
        const float F = sigm(a1A[nt][1] + a1B[nt][1]);                          \
        const float G = tanh_(a1A[nt][2] + a1B[nt][2]);                         \
        const float O = sigm(a1A[nt][3] + a1B[nt][3]);                          \
        c1[nt] = fmaf(F, c1[nt], I * G);                                        \
        const float h = O * tanh_(c1[nt]);                                      \
        const unsigned short hh = bf16_rne(h);                                  \
        const unsigned short hl = bf16_rne(h - bf16_f(hh));                     \
        if (col < MB) {                                                         \
            const int o = nt ? off1b : off1a;                                   \
            zz[NP][0][o] = hh;                                                  \
            zz[NP][1][o] = hl;                                                  \
        }                                                                       \
    }

#define STEP_ACT2(NP)                                                           \
    {                                                                           \
        const float I = sigm(ac2a[0] + ac2b[0]);                                \
        const float F = sigm(ac2a[1] + ac2b[1]);                                \
        const float G = tanh_(ac2a[2] + ac2b[2]);                               \
        const float O = sigm(ac2a[3] + ac2b[3]);                                \
        c2 = fmaf(F, c2, I * G);                                                \
        const float h = O * tanh_(c2);                                          \
        if (col < MB) {                                                         \
            const unsigned short hh = bf16_rne(h);                              \
            zz[NP][0][off2] = hh;                                               \
            zz[NP][1][off2] = bf16_rne(h - bf16_f(hh));                         \
        }                                                                       \
    }

__global__ __launch_bounds__(BLK, 2)
void lstm_mfma(const float* __restrict__ x,
               const float* __restrict__ Wih1, const float* __restrict__ Whh1,
               const float* __restrict__ bih1, const float* __restrict__ bhh1,
               const float* __restrict__ Wih2, const float* __restrict__ Whh2,
               const float* __restrict__ bih2, const float* __restrict__ bhh2,
               const float* __restrict__ fc1_w, const float* __restrict__ fc1_b,
               const float* __restrict__ fc2_w, const float* __restrict__ fc2_b,
               float* __restrict__ out)
{
    __shared__ __align__(16) unsigned short zz[2][2][2048];  // [pp][hi/lo][4ks*512] 16 KB
    __shared__ __align__(16) float h2f[MB * H2];
    __shared__ __align__(16) float fcs[MB * FCN];

    const int t    = threadIdx.x;
    const int lane = t & 63;
    const int w    = t >> 6;      // wave 0..7
    const int col  = lane & 15;   // batch col (valid < MB) / A-frag row
    const int quad = lane >> 4;
    const int b0   = blockIdx.x * MB;

    // ---- weight fragments (gate-complete interleaved mapping) ----
    S8U wf1h[2][3], wf1l[2][3];   // layer1: 2 tiles x ks 0..2
    S8U wf2h[3],    wf2l[3];      // layer2: 1 tile  x ks {0,1,3}
    #pragma unroll
    for (int nt = 0; nt < 2; ++nt) {
        const int r1 = (col & 3) * 64 + w * 8 + nt * 4 + (col >> 2);
        #pragma unroll
        for (int ks = 0; ks < 3; ++ks) {
            #pragma unroll
            for (int j = 0; j < 8; ++j) {
                const int k = ks * 32 + quad * 8 + j;
                float wv;
                if      (k < H1)      wv = Whh1[r1 * H1 + k];
                else if (k < H1 + 4)  wv = Wih1[r1 * IN_F + (k - H1)];
                else if (k == 68)     wv = bih1[r1] + bhh1[r1];   // bias col
                else                  wv = 0.f;
                const unsigned short hh = bf16_rne(wv);
                wf1h[nt][ks].u[j] = hh;
                wf1l[nt][ks].u[j] = bf16_rne(wv - bf16_f(hh));
            }
        }
    }
    {
        const int r2 = (col & 3) * 32 + w * 4 + (col >> 2);
        #pragma unroll
        for (int kf = 0; kf < 3; ++kf) {
            #pragma unroll
            for (int j = 0; j < 8; ++j) {
                const int k = ((kf < 2) ? kf * 32 : 96) + quad * 8 + j;
                const float wv = (k < H1) ? Wih2[r2 * H1 + k]
                                          : Whh2[r2 * H2 + (k - 96)];
                const unsigned short hh = bf16_rne(wv);
                wf2h[kf].u[j] = hh;
                wf2l[kf].u[j] = bf16_rne(wv - bf16_f(hh));
            }
        }
    }
    // layer2 biases as MFMA C-init vector (lane's unit u2 = w*4+quad)
    const int u2 = w * 4 + quad;
    F4U bb2;
    bb2.f[0] = bih2[u2]      + bhh2[u2];
    bb2.f[1] = bih2[32 + u2] + bhh2[32 + u2];
    bb2.f[2] = bih2[64 + u2] + bhh2[64 + u2];
    bb2.f[3] = bih2[96 + u2] + bhh2[96 + u2];

    // ---- PIN fragments + bias into AGPRs (kills in-loop rematerialization) ----
    #pragma unroll
    for (int nt = 0; nt < 2; ++nt)
        #pragma unroll
        for (int ks = 0; ks < 3; ++ks) { APIN4(wf1h[nt][ks]); APIN4(wf1l[nt][ks]); }
    #pragma unroll
    for (int kf = 0; kf < 3; ++kf) { APIN4(wf2h[kf]); APIN4(wf2l[kf]); }
    APIN4(bb2);

    // ---- init LDS: zero z; bias-one col (both pp); x(0) ----
    {
        int* pz = (int*)zz;
        #pragma unroll
        for (int i = 0; i < 8; ++i) pz[t + i * BLK] = 0;
    }
    __syncthreads();
    if (t < 16) {                           // off(k=68,n) = 1024 + n*8 + 4
        zz[0][0][1024 + t * 8 + 4] = 0x3F80;
        zz[1][0][1024 + t * 8 + 4] = 0x3F80;
    }
    if (t < MB * IN_F) {                    // x(0) at k=64+f: off = 1024 + n*8 + f
        const int n = t >> 2, f = t & 3;
        const float xv = x[(size_t)(b0 + n) * T_LEN * IN_F + f];
        const unsigned short xh = bf16_rne(xv);
        zz[0][0][1024 + n * 8 + f] = xh;
        zz[0][1][1024 + n * 8 + f] = bf16_rne(xv - bf16_f(xh));
    }
    float c1[2] = {0.f, 0.f};   // layer1 units w*8+nt*4+quad, batch col
    float c2    = 0.f;          // layer2 unit  u2,            batch col

    // precomputed store offsets (element index); h1 now at k = unit
    const int u1a  = w * 8 + quad;
    const int u1b  = w * 8 + 4 + quad;
    const int off1a = (u1a >> 5) * 512 + (((u1a >> 3) & 3) * 16 + col) * 8 + (u1a & 7);
    const int off1b = (u1b >> 5) * 512 + (((u1b >> 3) & 3) * 16 + col) * 8 + (u1b & 7);
    const int off2  = 1536 + (((u2 >> 3) & 3) * 16 + col) * 8 + (u2 & 7);
    const int offF  = lane * 8;                    // frag read base
    const int xn_   = (t >> 2) & 7, xf_ = t & 3;   // x-prefetch role (t < 32)
    const float* xp = x + (size_t)(b0 + xn_) * T_LEN * IN_F + IN_F + xf_;  // -> x(1)
    __syncthreads();

    // ================= main recurrence: unrolled x2, 1 barrier/step ==========
    #pragma unroll 1
    for (int s2 = 0; s2 < T_LEN / 2; ++s2) {
        // ---------- body A: s = 2*s2 (read zz[0], write zz[1]) ----------
        {
            float xn = 0.f;
            if (t < MB * IN_F) xn = *xp;           // x(2*s2+1), always valid
            STEP_MFMA(0)
            STEP_ACT1(1)
            if (s2 != 0) STEP_ACT2(1)              // gates2 belong to step s-1
            if (t < MB * IN_F) {
                const unsigned short xh = bf16_rne(xn);
                zz[1][0][1024 + xn_ * 8 + xf_] = xh;
                zz[1][1][1024 + xn_ * 8 + xf_] = bf16_rne(xn - bf16_f(xh));
            }
            xp += IN_F;
        }
        __syncthreads();
        // ---------- body B: s = 2*s2+1 (read zz[1], write zz[0]) ----------
        {
            float xn = 0.f;
            const bool ld = (t < MB * IN_F) && (s2 != T_LEN / 2 - 1);
            if (ld) xn = *xp;                      // x(2*s2+2)
            STEP_MFMA(1)
            STEP_ACT1(0)
            STEP_ACT2(0)                           // s >= 1 always here
            if (ld) {
                const unsigned short xh = bf16_rne(xn);
                zz[0][0][1024 + xn_ * 8 + xf_] = xh;
                zz[0][1][1024 + xn_ * 8 + xf_] = bf16_rne(xn - bf16_f(xh));
            }
            xp += IN_F;
        }
        __syncthreads();
    }

    // ================= epilogue: layer2 step T-1 (zz[0]: h1(511), h2(510)) ====
    {
        f4 ac2a = bb2.v, ac2b = {0,0,0,0};
        #pragma unroll
        for (int kf = 0; kf < 3; ++kf) {
            const int zks = (kf < 2) ? kf : 3;
            const s8b zh = *(const s8b*)(&zz[0][0][0] + zks * 512 + offF);
            const s8b zl = *(const s8b*)(&zz[0][1][0] + zks * 512 + offF);
            ac2a = __builtin_amdgcn_mfma_f32_16x16x32_bf16(wf2h[kf].v, zh, ac2a, 0, 0, 0);
            ac2b = __builtin_amdgcn_mfma_f32_16x16x32_bf16(wf2h[kf].v, zl, ac2b, 0, 0, 0);
            ac2b = __builtin_amdgcn_mfma_f32_16x16x32_bf16(wf2l[kf].v, zh, ac2b, 0, 0, 0);
        }
        const float I = sigm(ac2a[0] + ac2b[0]);
        const float F = sigm(ac2a[1] + ac2b[1]);
        const float G = tanh_(ac2a[2] + ac2b[2]);
        const float O = sigm(ac2a[3] + ac2b[3]);
        c2 = fmaf(F, c2, I * G);
        if (col < MB) h2f[col * H2 + u2] = O * tanh_(c2);
    }
    __syncthreads();

    // ================= FC head =================
    if (t < MB * FCN) {
        const int b = t >> 4, j = t & 15;
        float s1 = fc1_b[j];
        #pragma unroll
        for (int k = 0; k < H2; ++k)
            s1 = fmaf(fc1_w[j * H2 + k], h2f[b * H2 + k], s1);
        fcs[b * FCN + j] = fmaxf(s1, 0.f);
    }
    __syncthreads();
    if (t < MB) {
        float s2v = fc2_b[0];
        #pragma unroll
        for (int j = 0; j < FCN; ++j)
            s2v = fmaf(fc2_w[j], fcs[t * FCN + j], s2v);
        out[b0 + t] = s2v;
    }
}

extern "C" void kernel_launch(void* const* d_in, const int* in_sizes, int n_in,
                              void* d_out, int out_size, void* d_ws, size_t ws_size,
                              hipStream_t stream) {
    const float* x     = (const float*)d_in[0];
    const float* Wih1  = (const float*)d_in[1];
    const float* Whh1  = (const float*)d_in[2];
    const float* bih1  = (const float*)d_in[3];
    const float* bhh1  = (const float*)d_in[4];
    const float* Wih2  = (const float*)d_in[5];
    const float* Whh2  = (const float*)d_in[6];
    const float* bih2  = (const float*)d_in[7];
    const float* bhh2  = (const float*)d_in[8];
    const float* fc1_w = (const float*)d_in[9];
    const float* fc1_b = (const float*)d_in[10];
    const float* fc2_w = (const float*)d_in[11];
    const float* fc2_b = (const float*)d_in[12];
    float* out = (float*)d_out;

    const int n_batch = 2048;
    dim3 grid(n_batch / MB), block(BLK);
    lstm_mfma<<<grid, block, 0, stream>>>(x, Wih1, Whh1, bih1, bhh1,
                                          Wih2, Whh2, bih2, bhh2,
                                          fc1_w, fc1_b, fc2_w, fc2_b, out);
}